// Round 8
// baseline (20687.209 us; speedup 1.0000x reference)
//
#include <hip/hip_runtime.h>
#include <math.h>

#define N_NODES 25000
#define N_EDGES 400000
#define H 128
#define D_EA 64
#define M_MSG 192
#define L_LAYERS 3
#define POS_CLIPV 10.0

__device__ inline double sigd(double x){ return 1.0/(1.0+exp(-x)); }
__device__ inline double silud(double x){ return x/(1.0+exp(-x)); }

// ---------------- CSR build ----------------
__global__ void k_hist(const int* dst, int* cnt){
  int e = blockIdx.x*256 + threadIdx.x;
  if(e<N_EDGES) atomicAdd(&cnt[dst[e]],1);
}
__global__ void __launch_bounds__(1024) k_scan(const int* cnt, int* row_ptr){
  __shared__ int part[1024];
  int tid = threadIdx.x;
  const int CH = 25;
  int base = tid*CH;
  int s=0;
  for(int i=0;i<CH;i++){ int idx=base+i; if(idx<N_NODES) s += cnt[idx]; }
  part[tid]=s;
  __syncthreads();
  for(int off=1; off<1024; off<<=1){
    int v = (tid>=off)? part[tid-off] : 0;
    __syncthreads();
    part[tid]+=v;
    __syncthreads();
  }
  int run = part[tid]-s;
  for(int i=0;i<CH;i++){
    int idx=base+i;
    if(idx<=N_NODES){ row_ptr[idx]=run; if(idx<N_NODES) run += cnt[idx]; }
  }
}
__global__ void k_scatter(const int* dst, const int* row_ptr, int* cursor, int* edge_ids){
  int e = blockIdx.x*256+threadIdx.x;
  if(e<N_EDGES){
    int d = dst[e];
    int off = atomicAdd(&cursor[d],1);
    edge_ids[row_ptr[d]+off]=e;
  }
}

// ---------------- init f32 -> f64 ----------------
__global__ void k_x_init(const float* x_in, double* xd){
  int i = blockIdx.x*256 + threadIdx.x;
  if(i < N_NODES*H) xd[i] = (double)x_in[i];
}
__global__ void k_pos_init(const float* pos_in, double* pos_d){
  int i = blockIdx.x*256 + threadIdx.x;
  if(i < N_NODES*3) pos_d[i] = (double)pos_in[i];
}

// ---------------- node LN (f64) ----------------
__global__ void __launch_bounds__(256) k_node_ln_d(const double* xd,
                          const float* gx, const float* bx, double* xnd){
  int wave = threadIdx.x>>6, lane = threadIdx.x&63;
  int n = blockIdx.x*4 + wave;
  double v0 = xd[(size_t)n*H + lane], v1 = xd[(size_t)n*H + 64 + lane];
  double s = v0+v1, ss = v0*v0+v1*v1;
  #pragma unroll
  for(int w=1; w<64; w<<=1){ s += __shfl_xor(s,w); ss += __shfl_xor(ss,w); }
  double m = s/(double)H;
  double var = ss/(double)H - m*m;
  double rstd = 1.0/sqrt(var + 1e-6);
  xnd[(size_t)n*H+lane]    = (v0-m)*rstd*(double)gx[lane]    + (double)bx[lane];
  xnd[(size_t)n*H+64+lane] = (v1-m)*rstd*(double)gx[64+lane] + (double)bx[64+lane];
}

// ---------------- pos LN (f64, two-pass var) ----------------
__global__ void k_pn_d(const double* pos_d, const float* gp, const float* bp, double* pnd){
  int n = blockIdx.x*256 + threadIdx.x;
  if(n >= N_NODES) return;
  double p0=pos_d[n*3], p1=pos_d[n*3+1], p2=pos_d[n*3+2];
  double mp=(p0+p1+p2)/3.0;
  double d0=p0-mp, d1=p1-mp, d2=p2-mp;
  double vp=(d0*d0+d1*d1+d2*d2)/3.0;
  double rp=1.0/sqrt(vp + 1e-6);
  pnd[n*3]   = d0*rp*(double)gp[0]+(double)bp[0];
  pnd[n*3+1] = d1*rp*(double)gp[1]+(double)bp[1];
  pnd[n*3+2] = d2*rp*(double)gp[2]+(double)bp[2];
}

// ---------------- fused per-edge MLP, full f64 ----------------
// 16 edges/block, 256 threads. thread (r=tid>>4, q=tid&15): edge r, cols {q+16j}.
// attn (raw msg) -> va (vw*attn) -> scalar (ln1->w1->silu->w2->ln2*attn) -> atomic aggr.
__global__ void __launch_bounds__(256) k_edge_d(
    const int* ei, const double* xnd, const float* ea,
    const float* a_w1, const float* a_b1, const float* a_w2, const float* a_b2,
    const float* s_ln1_g, const float* s_ln1_b, const float* s_w1, const float* s_b1,
    const float* s_w2, const float* s_b2, const float* s_ln2_g, const float* s_ln2_b,
    const float* v_ln_g, const float* v_ln_b, const float* v_w1, const float* v_b1,
    const float* v_w2, const float* v_b2,
    double* aggr_d, double* va_d){

  __shared__ double msgS[16][194];   // raw msg, then core=(raw-m)*rstd; aliased by usS late
  __shared__ double Wc[32][128];     // weight chunk
  __shared__ double lnp[4][192];     // v_ln_g, v_ln_b, s_ln1_g, s_ln1_b
  __shared__ double atS[16];
  double (*usS)[130] = (double(*)[130])msgS;

  const int tid = threadIdx.x;
  const int r = tid>>4, q = tid&15;
  const int e = blockIdx.x*16 + r;
  const int src = ei[e];
  const int dst = ei[N_EDGES + e];

  // stage LN params (4 x 192 = 768 doubles)
  #pragma unroll
  for(int j=0;j<3;j++){
    int i = tid + 256*j;
    int row = i/192, col = i%192;
    const float* sp = (row==0)? v_ln_g : (row==1)? v_ln_b : (row==2)? s_ln1_g : s_ln1_b;
    ((double*)lnp)[i] = (double)sp[col];
  }

  // load msg + stats
  double mv[12];
  double s=0, ss=0;
  #pragma unroll
  for(int j=0;j<12;j++){
    int k = q + 16*j;
    double v = (k<H)? xnd[(size_t)src*H + k] : (double)ea[(size_t)e*D_EA + (k-H)];
    mv[j]=v; s+=v; ss+=v*v;
  }
  #pragma unroll
  for(int w=1;w<16;w<<=1){ s += __shfl_xor(s,w); ss += __shfl_xor(ss,w); }
  double m = s/(double)M_MSG;
  double var = ss/(double)M_MSG - m*m;
  double rstd = 1.0/sqrt(var + 1e-6);
  #pragma unroll
  for(int j=0;j<12;j++) msgS[r][q+16*j] = mv[j];
  __syncthreads();

  // ---- ATTN path (raw msg @ a_w1) ----
  double acc[8];
  #pragma unroll
  for(int j=0;j<8;j++) acc[j] = (double)a_b1[q+16*j];
  for(int kc=0;kc<6;kc++){
    __syncthreads();
    #pragma unroll
    for(int t=0;t<16;t++){ int i = tid + 256*t; Wc[i>>7][i&127] = (double)a_w1[(size_t)(kc*32 + (i>>7))*H + (i&127)]; }
    __syncthreads();
    for(int k=0;k<32;k++){
      double x = msgS[r][kc*32+k];
      #pragma unroll
      for(int j=0;j<8;j++) acc[j] = fma(x, Wc[k][q+16*j], acc[j]);
    }
  }
  double su = 0;
  #pragma unroll
  for(int j=0;j<8;j++) su += silud(acc[j]) * (double)a_w2[q+16*j];
  #pragma unroll
  for(int w=1;w<16;w<<=1) su += __shfl_xor(su,w);
  double at = sigd(su + (double)a_b2[0]);
  if(q==0) atS[r] = at;

  // transform own row: core = (raw-m)*rstd  (row r touched only by its own wave -> safe)
  #pragma unroll
  for(int j=0;j<12;j++) msgS[r][q+16*j] = (mv[j]-m)*rstd;

  // ---- V path (ln_v(msg) @ v_w1) ----
  #pragma unroll
  for(int j=0;j<8;j++) acc[j] = (double)v_b1[q+16*j];
  for(int kc=0;kc<6;kc++){
    __syncthreads();
    #pragma unroll
    for(int t=0;t<16;t++){ int i = tid + 256*t; Wc[i>>7][i&127] = (double)v_w1[(size_t)(kc*32+(i>>7))*H + (i&127)]; }
    __syncthreads();
    for(int k=0;k<32;k++){
      int kg = kc*32+k;
      double x = fma(msgS[r][kg], lnp[0][kg], lnp[1][kg]);
      #pragma unroll
      for(int j=0;j<8;j++) acc[j] = fma(x, Wc[k][q+16*j], acc[j]);
    }
  }
  {
    double sv = 0;
    #pragma unroll
    for(int j=0;j<8;j++) sv += silud(acc[j]) * (double)v_w2[q+16*j];
    #pragma unroll
    for(int w=1;w<16;w<<=1) sv += __shfl_xor(sv,w);
    if(q==0) va_d[e] = (sv + (double)v_b2[0]) * at;
  }

  // ---- S path part 1 (ln_s(msg) @ s_w1 + s_b1 -> silu) ----
  #pragma unroll
  for(int j=0;j<8;j++) acc[j] = (double)s_b1[q+16*j];
  for(int kc=0;kc<6;kc++){
    __syncthreads();
    #pragma unroll
    for(int t=0;t<16;t++){ int i = tid + 256*t; Wc[i>>7][i&127] = (double)s_w1[(size_t)(kc*32+(i>>7))*H + (i&127)]; }
    __syncthreads();
    for(int k=0;k<32;k++){
      int kg = kc*32+k;
      double x = fma(msgS[r][kg], lnp[2][kg], lnp[3][kg]);
      #pragma unroll
      for(int j=0;j<8;j++) acc[j] = fma(x, Wc[k][q+16*j], acc[j]);
    }
  }
  double us[8];
  #pragma unroll
  for(int j=0;j<8;j++) us[j] = silud(acc[j]);
  __syncthreads();             // all msgS reads complete block-wide before usS overwrite
  #pragma unroll
  for(int j=0;j<8;j++) usS[r][q+16*j] = us[j];

  // ---- S path part 2 (us @ s_w2 + s_b2) ----
  #pragma unroll
  for(int j=0;j<8;j++) acc[j] = (double)s_b2[q+16*j];
  for(int kc=0;kc<4;kc++){
    __syncthreads();
    #pragma unroll
    for(int t=0;t<16;t++){ int i = tid + 256*t; Wc[i>>7][i&127] = (double)s_w2[(size_t)(kc*32+(i>>7))*H + (i&127)]; }
    __syncthreads();
    for(int k=0;k<32;k++){
      double x = usS[r][kc*32+k];
      #pragma unroll
      for(int j=0;j<8;j++) acc[j] = fma(x, Wc[k][q+16*j], acc[j]);
    }
  }
  // ---- ln2 * attn -> atomic aggregate ----
  {
    double sh=0, ssh=0;
    #pragma unroll
    for(int j=0;j<8;j++){ sh += acc[j]; ssh += acc[j]*acc[j]; }
    #pragma unroll
    for(int w=1;w<16;w<<=1){ sh += __shfl_xor(sh,w); ssh += __shfl_xor(ssh,w); }
    double m2 = sh/(double)H;
    double var2 = ssh/(double)H - m2*m2;
    double rstd2 = 1.0/sqrt(var2 + 1e-6);
    double atAll = atS[r];
    #pragma unroll
    for(int j=0;j<8;j++){
      int col = q+16*j;
      double sc = ((acc[j]-m2)*rstd2*(double)s_ln2_g[col] + (double)s_ln2_b[col]) * atAll;
      atomicAdd(&aggr_d[(size_t)dst*H + col], sc);
    }
  }
}

// ---------------- gate + x update (f64) ----------------
__global__ void __launch_bounds__(256) k_update_d(const double* xnd, const double* aggr,
                       const float* g_w, const float* g_b, double* xd){
  __shared__ double y[4][256];
  __shared__ double gwt[32][128];
  int wave = threadIdx.x>>6, lane = threadIdx.x&63;
  int n = blockIdx.x*4 + wave;
  double xn0 = xnd[(size_t)n*H+lane], xn1 = xnd[(size_t)n*H+64+lane];
  double s0 = aggr[(size_t)n*H+lane], s1 = aggr[(size_t)n*H+64+lane];
  y[wave][lane]=xn0; y[wave][64+lane]=xn1; y[wave][128+lane]=s0; y[wave][192+lane]=s1;
  __syncthreads();
  double g0=0, g1=0;
  for(int kc=0; kc<8; kc++){
    #pragma unroll
    for(int j=0;j<16;j++){
      int idx = threadIdx.x + 256*j;
      gwt[idx>>7][idx&127] = (double)g_w[(size_t)(kc*32+(idx>>7))*H + (idx&127)];
    }
    __syncthreads();
    #pragma unroll
    for(int k=0;k<32;k++){
      double yk = y[wave][kc*32+k];
      g0 = fma(yk, gwt[k][lane],    g0);
      g1 = fma(yk, gwt[k][64+lane], g1);
    }
    __syncthreads();
  }
  g0 = sigd(g0 + (double)g_b[lane]); g1 = sigd(g1 + (double)g_b[64+lane]);
  xd[(size_t)n*H+lane]    = xn0*(1.0-g0) + s0*g0;
  xd[(size_t)n*H+64+lane] = xn1*(1.0-g1) + s1*g1;
}

// ---------------- pos aggregate + update (f64) ----------------
__global__ void k_pos_aggr_d(const int* row_ptr, const int* edge_ids, const int* ei,
                             const double* va_d, const double* pnd, double* pos_d){
  int n = blockIdx.x*256 + threadIdx.x;
  if(n >= N_NODES) return;
  double q0=pnd[n*3], q1=pnd[n*3+1], q2=pnd[n*3+2];
  double a0=0, a1=0, a2=0;
  int st = row_ptr[n], en = row_ptr[n+1];
  for(int idx=st; idx<en; idx++){
    int e = edge_ids[idx];
    int srcn = ei[e];
    double r0=pnd[srcn*3]-q0, r1=pnd[srcn*3+1]-q1, r2=pnd[srcn*3+2]-q2;
    double dist = fmax(sqrt(r0*r0+r1*r1+r2*r2), 1e-6);
    double wv = va_d[e]/dist;
    a0 = fma(wv,r0,a0); a1 = fma(wv,r1,a1); a2 = fma(wv,r2,a2);
  }
  pos_d[n*3]   = fmin(fmax(q0+a0,-POS_CLIPV),POS_CLIPV);
  pos_d[n*3+1] = fmin(fmax(q1+a1,-POS_CLIPV),POS_CLIPV);
  pos_d[n*3+2] = fmin(fmax(q2+a2,-POS_CLIPV),POS_CLIPV);
}

// ---------------- energy head (f64 -> f32 out) ----------------
__global__ void __launch_bounds__(256) k_energy_d(const double* xd,
                         const float* e_w1, const float* e_b1,
                         const float* e_w2, const float* e_b2, float* out){
  __shared__ double y[4][128];
  __shared__ double h[4][128];
  int wave = threadIdx.x>>6, lane = threadIdx.x&63;
  int n = blockIdx.x*4 + wave;
  y[wave][lane]=xd[(size_t)n*H+lane]; y[wave][64+lane]=xd[(size_t)n*H+64+lane];
  __syncthreads();
  double h0=(double)e_b1[lane], h1=(double)e_b1[64+lane];
  for(int k=0;k<H;k++){
    double yk=y[wave][k];
    h0 = fma(yk, (double)e_w1[k*H+lane],    h0);
    h1 = fma(yk, (double)e_w1[k*H+64+lane], h1);
  }
  h[wave][lane]=fmax(h0,0.0); h[wave][64+lane]=fmax(h1,0.0);
  __syncthreads();
  double o0=(double)e_b2[lane], o1=(double)e_b2[64+lane];
  for(int k=0;k<H;k++){
    double hk=h[wave][k];
    o0 = fma(hk, (double)e_w2[k*H+lane],    o0);
    o1 = fma(hk, (double)e_w2[k*H+64+lane], o1);
  }
  out[(size_t)n*H+lane]=(float)o0; out[(size_t)n*H+64+lane]=(float)o1;
}

__global__ void k_poscopy_d(const double* pos_d, float* out){
  int i = blockIdx.x*256+threadIdx.x;
  if(i<N_NODES*3) out[i]=(float)pos_d[i];
}

// ---------------- launch ----------------
extern "C" void kernel_launch(void* const* d_in, const int* in_sizes, int n_in,
                              void* d_out, int out_size, void* d_ws, size_t ws_size,
                              hipStream_t stream){
  const float* x_in   = (const float*)d_in[0];
  const float* pos_in = (const float*)d_in[1];
  const int*   ei     = (const int*)  d_in[2];
  const float* ea     = (const float*)d_in[3];
  const float* ln_x_g = (const float*)d_in[4];
  const float* ln_x_b = (const float*)d_in[5];
  const float* ln_p_g = (const float*)d_in[6];
  const float* ln_p_b = (const float*)d_in[7];
  const float* s_ln1_g= (const float*)d_in[8];
  const float* s_ln1_b= (const float*)d_in[9];
  const float* s_w1   = (const float*)d_in[10];
  const float* s_b1   = (const float*)d_in[11];
  const float* s_w2   = (const float*)d_in[12];
  const float* s_b2   = (const float*)d_in[13];
  const float* s_ln2_g= (const float*)d_in[14];
  const float* s_ln2_b= (const float*)d_in[15];
  const float* v_ln_g = (const float*)d_in[16];
  const float* v_ln_b = (const float*)d_in[17];
  const float* v_w1   = (const float*)d_in[18];
  const float* v_b1   = (const float*)d_in[19];
  const float* v_w2   = (const float*)d_in[20];
  const float* v_b2   = (const float*)d_in[21];
  const float* a_w1   = (const float*)d_in[22];
  const float* a_b1   = (const float*)d_in[23];
  const float* a_w2   = (const float*)d_in[24];
  const float* a_b2   = (const float*)d_in[25];
  const float* g_w    = (const float*)d_in[26];
  const float* g_b    = (const float*)d_in[27];
  const float* e_w1   = (const float*)d_in[28];
  const float* e_b1   = (const float*)d_in[29];
  const float* e_w2   = (const float*)d_in[30];
  const float* e_b2   = (const float*)d_in[31];

  char* w = (char*)d_ws;
  auto alloc=[&](size_t bytes)->char*{ char* p=w; w += (bytes+255)&~(size_t)255; return p; };
  double* xd     = (double*)alloc((size_t)N_NODES*H*8);
  double* xnd    = (double*)alloc((size_t)N_NODES*H*8);
  double* aggr_d = (double*)alloc((size_t)N_NODES*H*8);
  double* pos_d  = (double*)alloc((size_t)N_NODES*3*8);
  double* pnd    = (double*)alloc((size_t)N_NODES*3*8);
  double* va_d   = (double*)alloc((size_t)N_EDGES*8);
  int* row_ptr   = (int*)alloc((size_t)(N_NODES+1)*4);
  int* cnt       = (int*)alloc((size_t)N_NODES*4);
  int* cursor    = (int*)alloc((size_t)N_NODES*4);
  int* edge_ids  = (int*)alloc((size_t)N_EDGES*4);

  hipMemsetAsync(cnt,   0, (size_t)N_NODES*4, stream);
  hipMemsetAsync(cursor,0, (size_t)N_NODES*4, stream);
  k_x_init  <<<(N_NODES*H+255)/256,256,0,stream>>>(x_in, xd);
  k_pos_init<<<(N_NODES*3+255)/256,256,0,stream>>>(pos_in, pos_d);

  const int* dstp = ei + N_EDGES;
  k_hist   <<<(N_EDGES+255)/256,256,0,stream>>>(dstp,cnt);
  k_scan   <<<1,1024,0,stream>>>(cnt,row_ptr);
  k_scatter<<<(N_EDGES+255)/256,256,0,stream>>>(dstp,row_ptr,cursor,edge_ids);

  for(int l=0;l<L_LAYERS;l++){
    k_node_ln_d<<<N_NODES/4,256,0,stream>>>(xd, ln_x_g+l*H, ln_x_b+l*H, xnd);
    k_pn_d<<<(N_NODES+255)/256,256,0,stream>>>(pos_d, ln_p_g+l*3, ln_p_b+l*3, pnd);
    hipMemsetAsync(aggr_d, 0, (size_t)N_NODES*H*8, stream);
    k_edge_d<<<N_EDGES/16,256,0,stream>>>(ei, xnd, ea,
        a_w1 + (size_t)l*M_MSG*H, a_b1 + l*H, a_w2 + l*H, a_b2 + l,
        s_ln1_g + l*M_MSG, s_ln1_b + l*M_MSG, s_w1 + (size_t)l*M_MSG*H, s_b1 + l*H,
        s_w2 + (size_t)l*H*H, s_b2 + l*H, s_ln2_g + l*H, s_ln2_b + l*H,
        v_ln_g + l*M_MSG, v_ln_b + l*M_MSG, v_w1 + (size_t)l*M_MSG*H, v_b1 + l*H,
        v_w2 + l*H, v_b2 + l,
        aggr_d, va_d);
    k_update_d<<<N_NODES/4,256,0,stream>>>(xnd, aggr_d,
        g_w + (size_t)l*2*H*H, g_b + l*H, xd);
    k_pos_aggr_d<<<(N_NODES+255)/256,256,0,stream>>>(row_ptr, edge_ids, ei,
        va_d, pnd, pos_d);
  }
  k_energy_d<<<N_NODES/4,256,0,stream>>>(xd, e_w1, e_b1, e_w2, e_b2, (float*)d_out);
  k_poscopy_d<<<(N_NODES*3+255)/256,256,0,stream>>>(pos_d, (float*)d_out + (size_t)N_NODES*H);
}